// Round 1
// baseline (1468.198 us; speedup 1.0000x reference)
//
#include <hip/hip_runtime.h>
#include <math.h>

#define D_MODEL 1024
#define D_INNER 2048
#define D_STATE 16
#define D_CONV  4
#define DT_RANK 64
#define BB      2
#define LL      1024
#define BL      (BB*LL)   // 2048 rows (B*L)

__device__ __forceinline__ float sigmoidf_(float x) { return 1.0f / (1.0f + __expf(-x)); }

// ---------------------------------------------------------------------------
// Generic fp32 GEMM: C[M,N] = A[M,K] @ B[K,N], tile 64x64, BK=16, 4x4/thread.
// EPI==1: C = softplus(acc + bias[col])  (for delta)
// M must be a multiple of 64, K a multiple of 16. N guarded.
// ---------------------------------------------------------------------------
template<int EPI>
__global__ __launch_bounds__(256)
void gemm_f32(const float* __restrict__ A, const float* __restrict__ B,
              float* __restrict__ C, const float* __restrict__ bias,
              int M, int N, int K, int lda, int ldb, int ldc) {
    __shared__ float As[16][65];   // [k][row], padded (+1) to avoid bank conflicts
    __shared__ float Bs[16][64];   // [k][col]

    const int tid = threadIdx.x;
    const int tx = tid & 15;        // 0..15 -> col group
    const int ty = tid >> 4;        // 0..15 -> row group
    const int row0 = blockIdx.y * 64;
    const int col0 = blockIdx.x * 64;

    const int arow = tid >> 4;      // 0..15
    const int acol = tid & 15;      // k within tile
    const int brow = tid >> 6;      // 0..3
    const int bcol = tid & 63;

    float acc[4][4] = {};

    for (int k0 = 0; k0 < K; k0 += 16) {
        #pragma unroll
        for (int p = 0; p < 4; ++p) {
            int r = arow + p * 16;
            As[acol][r] = A[(size_t)(row0 + r) * lda + (k0 + acol)];
        }
        int gc = col0 + bcol;
        #pragma unroll
        for (int p = 0; p < 4; ++p) {
            int r = brow + p * 4;
            Bs[r][bcol] = (gc < N) ? B[(size_t)(k0 + r) * ldb + gc] : 0.0f;
        }
        __syncthreads();
        #pragma unroll
        for (int kk = 0; kk < 16; ++kk) {
            float a[4];
            #pragma unroll
            for (int i = 0; i < 4; ++i) a[i] = As[kk][ty * 4 + i];
            float4 bv = *reinterpret_cast<const float4*>(&Bs[kk][tx * 4]);
            float b4[4] = {bv.x, bv.y, bv.z, bv.w};
            #pragma unroll
            for (int i = 0; i < 4; ++i)
                #pragma unroll
                for (int j = 0; j < 4; ++j)
                    acc[i][j] = fmaf(a[i], b4[j], acc[i][j]);
        }
        __syncthreads();
    }

    #pragma unroll
    for (int i = 0; i < 4; ++i) {
        int gr = row0 + ty * 4 + i;
        #pragma unroll
        for (int j = 0; j < 4; ++j) {
            int gc = col0 + tx * 4 + j;
            if (gc < N) {
                float v = acc[i][j];
                if (EPI == 1) {
                    v += bias[gc];
                    v = (v > 20.0f) ? v : log1pf(__expf(v));
                }
                C[(size_t)gr * ldc + gc] = v;
            }
        }
    }
}

// ---------------------------------------------------------------------------
// Causal depthwise conv (K=4) + bias + SiLU.  xp = xz[:, 0:2048].
// u[bl, e] = silu( conv_b[e] + sum_k conv_w[e,k] * xp[b, l-3+k, e] )
// ---------------------------------------------------------------------------
__global__ __launch_bounds__(256)
void conv_silu(const float* __restrict__ xz, const float* __restrict__ conv_w,
               const float* __restrict__ conv_b, float* __restrict__ u) {
    int idx = blockIdx.x * 256 + threadIdx.x;
    if (idx >= BL * D_INNER) return;
    int e  = idx & (D_INNER - 1);
    int bl = idx >> 11;
    int b = bl >> 10, l = bl & (LL - 1);
    float acc = conv_b[e];
    #pragma unroll
    for (int k = 0; k < D_CONV; ++k) {
        int ll = l - (D_CONV - 1) + k;
        if (ll >= 0)
            acc = fmaf(conv_w[e * D_CONV + k],
                       xz[(size_t)(b * LL + ll) * (2 * D_INNER) + e], acc);
    }
    u[idx] = acc * sigmoidf_(acc);
}

// ---------------------------------------------------------------------------
// Selective scan. One lane per (b, e, n): 65536 lanes.
// h_{t} = exp(delta*A[e,n]) * h_{t-1} + delta * B[t,n] * u
// y_t   = sum_n h_t[n] * C[t,n];  out = (y + u*D) * silu(z)   (in-place over u)
// ---------------------------------------------------------------------------
__global__ __launch_bounds__(256)
void scan_kernel(const float* __restrict__ delta, const float* __restrict__ u_in,
                 const float* __restrict__ x_dbl, const float* __restrict__ xz,
                 const float* __restrict__ A_log, const float* __restrict__ D_skip,
                 float* __restrict__ ygated) {
    int g = blockIdx.x * 256 + threadIdx.x;   // 0..65535
    int n = g & (D_STATE - 1);
    int c = g >> 4;                           // (b, e)
    int e = c & (D_INNER - 1);
    int b = c >> 11;

    float A_en = -__expf(A_log[e * D_STATE + n]);
    float D_e  = D_skip[e];
    float h = 0.0f;

    const float* dptr = delta + (size_t)b * LL * D_INNER + e;
    const float* uptr = u_in  + (size_t)b * LL * D_INNER + e;
    const float* xdb  = x_dbl + (size_t)b * LL * 96;
    const float* zptr = xz    + (size_t)b * LL * (2 * D_INNER) + D_INNER + e;

    #pragma unroll 4
    for (int t = 0; t < LL; ++t) {
        float dv = dptr[(size_t)t * D_INNER];
        float uv = uptr[(size_t)t * D_INNER];
        float Bv = xdb[t * 96 + DT_RANK + n];
        float Cv = xdb[t * 96 + DT_RANK + D_STATE + n];
        float dA = __expf(dv * A_en);
        h = fmaf(dA, h, dv * Bv * uv);
        float part = h * Cv;
        part += __shfl_xor(part, 1);
        part += __shfl_xor(part, 2);
        part += __shfl_xor(part, 4);
        part += __shfl_xor(part, 8);
        if (n == 0) {
            float zv = zptr[(size_t)t * (2 * D_INNER)];
            float yg = (part + uv * D_e) * (zv * sigmoidf_(zv));
            ygated[(size_t)(b * LL + t) * D_INNER + e] = yg;
        }
    }
}

// ---------------------------------------------------------------------------
extern "C" void kernel_launch(void* const* d_in, const int* in_sizes, int n_in,
                              void* d_out, int out_size, void* d_ws, size_t ws_size,
                              hipStream_t stream) {
    const float* x      = (const float*)d_in[0];  // [B,L,1024]
    const float* W_in   = (const float*)d_in[1];  // [1024, 4096]
    const float* conv_w = (const float*)d_in[2];  // [2048,1,4]
    const float* conv_b = (const float*)d_in[3];  // [2048]
    const float* W_xp   = (const float*)d_in[4];  // [2048, 96]
    const float* W_dt   = (const float*)d_in[5];  // [64, 2048]
    const float* dt_b   = (const float*)d_in[6];  // [2048]
    const float* A_log  = (const float*)d_in[7];  // [2048,16]
    const float* D_skip = (const float*)d_in[8];  // [2048]
    const float* W_out  = (const float*)d_in[9];  // [2048, 1024]
    float* out = (float*)d_out;

    // workspace layout (floats)
    float* ws    = (float*)d_ws;
    float* xz    = ws;                              // 2048*4096 = 8M
    float* u     = xz + (size_t)BL * 2 * D_INNER;   // 2048*2048 = 4M
    float* x_dbl = u + (size_t)BL * D_INNER;        // 2048*96
    float* delta = x_dbl + (size_t)BL * 96;         // 2048*2048 = 4M
    // ygated aliases u (in-place in scan, safe: read-before-write per wave)

    dim3 blk(256);

    // 1) xz = x @ W_in       [2048 x 4096]
    {
        dim3 grid(4096 / 64, BL / 64);
        hipLaunchKernelGGL((gemm_f32<0>), grid, blk, 0, stream,
                           x, W_in, xz, nullptr, BL, 2 * D_INNER, D_MODEL,
                           D_MODEL, 2 * D_INNER, 2 * D_INNER);
    }
    // 2) u = silu(convdw(xp) + b)
    {
        int total = BL * D_INNER;
        hipLaunchKernelGGL(conv_silu, dim3((total + 255) / 256), blk, 0, stream,
                           xz, conv_w, conv_b, u);
    }
    // 3) x_dbl = u @ W_xp    [2048 x 96]
    {
        dim3 grid((96 + 63) / 64, BL / 64);
        hipLaunchKernelGGL((gemm_f32<0>), grid, blk, 0, stream,
                           u, W_xp, x_dbl, nullptr, BL, 96, D_INNER,
                           D_INNER, 96, 96);
    }
    // 4) delta = softplus(x_dbl[:, :64] @ W_dt + dt_bias)   [2048 x 2048]
    {
        dim3 grid(D_INNER / 64, BL / 64);
        hipLaunchKernelGGL((gemm_f32<1>), grid, blk, 0, stream,
                           x_dbl, W_dt, delta, dt_b, BL, D_INNER, DT_RANK,
                           96, D_INNER, D_INNER);
    }
    // 5) selective scan + gate (writes ygated in-place over u)
    {
        hipLaunchKernelGGL(scan_kernel, dim3(65536 / 256), blk, 0, stream,
                           delta, u, x_dbl, xz, A_log, D_skip, u);
    }
    // 6) out = ygated @ W_out   [2048 x 1024]
    {
        dim3 grid(D_MODEL / 64, BL / 64);
        hipLaunchKernelGGL((gemm_f32<0>), grid, blk, 0, stream,
                           u, W_out, out, nullptr, BL, D_MODEL, D_INNER,
                           D_INNER, D_MODEL, D_MODEL);
    }
}

// Round 2
// 873.648 us; speedup vs baseline: 1.6805x; 1.6805x over previous
//
#include <hip/hip_runtime.h>
#include <math.h>

#define D_MODEL 1024
#define D_INNER 2048
#define D_STATE 16
#define D_CONV  4
#define DT_RANK 64
#define BB      2
#define LL      1024
#define BL      (BB*LL)   // 2048 rows (B*L)
#define CHUNK   64
#define NCHUNK  (LL/CHUNK)   // 16
#define RECSTRIDE (BB*D_INNER*D_STATE)   // 65536 records per chunk

__device__ __forceinline__ float sigmoidf_(float x) { return 1.0f / (1.0f + __expf(-x)); }

// ---------------------------------------------------------------------------
// Generic fp32 GEMM: C[M,N] = A[M,K] @ B[K,N], tile 64x64, BK=16, 4x4/thread.
// EPI==1: C = softplus(acc + bias[col])  (for delta)
// ---------------------------------------------------------------------------
template<int EPI>
__global__ __launch_bounds__(256)
void gemm_f32(const float* __restrict__ A, const float* __restrict__ B,
              float* __restrict__ C, const float* __restrict__ bias,
              int M, int N, int K, int lda, int ldb, int ldc) {
    __shared__ float As[16][65];
    __shared__ float Bs[16][64];

    const int tid = threadIdx.x;
    const int tx = tid & 15;
    const int ty = tid >> 4;
    const int row0 = blockIdx.y * 64;
    const int col0 = blockIdx.x * 64;

    const int arow = tid >> 4;
    const int acol = tid & 15;
    const int brow = tid >> 6;
    const int bcol = tid & 63;

    float acc[4][4] = {};

    for (int k0 = 0; k0 < K; k0 += 16) {
        #pragma unroll
        for (int p = 0; p < 4; ++p) {
            int r = arow + p * 16;
            As[acol][r] = A[(size_t)(row0 + r) * lda + (k0 + acol)];
        }
        int gc = col0 + bcol;
        #pragma unroll
        for (int p = 0; p < 4; ++p) {
            int r = brow + p * 4;
            Bs[r][bcol] = (gc < N) ? B[(size_t)(k0 + r) * ldb + gc] : 0.0f;
        }
        __syncthreads();
        #pragma unroll
        for (int kk = 0; kk < 16; ++kk) {
            float a[4];
            #pragma unroll
            for (int i = 0; i < 4; ++i) a[i] = As[kk][ty * 4 + i];
            float4 bv = *reinterpret_cast<const float4*>(&Bs[kk][tx * 4]);
            float b4[4] = {bv.x, bv.y, bv.z, bv.w};
            #pragma unroll
            for (int i = 0; i < 4; ++i)
                #pragma unroll
                for (int j = 0; j < 4; ++j)
                    acc[i][j] = fmaf(a[i], b4[j], acc[i][j]);
        }
        __syncthreads();
    }

    #pragma unroll
    for (int i = 0; i < 4; ++i) {
        int gr = row0 + ty * 4 + i;
        #pragma unroll
        for (int j = 0; j < 4; ++j) {
            int gc = col0 + tx * 4 + j;
            if (gc < N) {
                float v = acc[i][j];
                if (EPI == 1) {
                    v += bias[gc];
                    v = (v > 20.0f) ? v : log1pf(__expf(v));
                }
                C[(size_t)gr * ldc + gc] = v;
            }
        }
    }
}

// ---------------------------------------------------------------------------
// Causal depthwise conv (K=4) + bias + SiLU.
// ---------------------------------------------------------------------------
__global__ __launch_bounds__(256)
void conv_silu(const float* __restrict__ xz, const float* __restrict__ conv_w,
               const float* __restrict__ conv_b, float* __restrict__ u) {
    int idx = blockIdx.x * 256 + threadIdx.x;
    if (idx >= BL * D_INNER) return;
    int e  = idx & (D_INNER - 1);
    int bl = idx >> 11;
    int b = bl >> 10, l = bl & (LL - 1);
    float acc = conv_b[e];
    #pragma unroll
    for (int k = 0; k < D_CONV; ++k) {
        int ll = l - (D_CONV - 1) + k;
        if (ll >= 0)
            acc = fmaf(conv_w[e * D_CONV + k],
                       xz[(size_t)(b * LL + ll) * (2 * D_INNER) + e], acc);
    }
    u[idx] = acc * sigmoidf_(acc);
}

// ---------------------------------------------------------------------------
// Chunked selective scan.
// Lane mapping (phase1/3): g = [b:1][c:4][e:11][n:4]  (n fastest)
//   -> 16 n-lanes + 4 e's per wave; B/C reads broadcast across e-groups.
// Record layout: rec[c*RECSTRIDE + ((b*E+e)*16+n)]
// ---------------------------------------------------------------------------
__global__ __launch_bounds__(256)
void scan_phase1(const float* __restrict__ delta, const float* __restrict__ u_in,
                 const float* __restrict__ x_dbl, const float* __restrict__ A_log,
                 float* __restrict__ dAprod, float* __restrict__ hend) {
    int g = blockIdx.x * 256 + threadIdx.x;          // 0 .. 2^20-1
    int n = g & 15;
    int e = (g >> 4) & (D_INNER - 1);
    int c = (g >> 15) & (NCHUNK - 1);
    int b = g >> 19;

    float A_en = -__expf(A_log[e * D_STATE + n]);
    float h = 0.0f, P = 1.0f;
    const int t0 = c * CHUNK;
    const float* dptr = delta + ((size_t)(b * LL + t0)) * D_INNER + e;
    const float* uptr = u_in  + ((size_t)(b * LL + t0)) * D_INNER + e;
    const float* xdb  = x_dbl + ((size_t)(b * LL + t0)) * 96 + DT_RANK + n;

    #pragma unroll 4
    for (int t = 0; t < CHUNK; ++t) {
        float dv = dptr[(size_t)t * D_INNER];
        float uv = uptr[(size_t)t * D_INNER];
        float Bv = xdb[t * 96];
        float dA = __expf(dv * A_en);
        h = fmaf(dA, h, dv * Bv * uv);
        P *= dA;
    }
    size_t rec = (size_t)c * RECSTRIDE + (((size_t)b * D_INNER + e) * D_STATE + n);
    dAprod[rec] = P;
    hend[rec] = h;
}

__global__ __launch_bounds__(256)
void scan_phase2(const float* __restrict__ dAprod, const float* __restrict__ hend,
                 float* __restrict__ hin) {
    int g = blockIdx.x * 256 + threadIdx.x;          // 0 .. 65535 == (b*E+e)*16+n
    float h = 0.0f;
    #pragma unroll
    for (int c = 0; c < NCHUNK; ++c) {
        size_t rec = (size_t)c * RECSTRIDE + g;
        hin[rec] = h;
        h = fmaf(dAprod[rec], h, hend[rec]);
    }
}

__global__ __launch_bounds__(256)
void scan_phase3(const float* __restrict__ delta, const float* __restrict__ u_in,
                 const float* __restrict__ x_dbl, const float* __restrict__ xz,
                 const float* __restrict__ A_log, const float* __restrict__ D_skip,
                 const float* __restrict__ hin, float* __restrict__ ygated) {
    int g = blockIdx.x * 256 + threadIdx.x;
    int n = g & 15;
    int e = (g >> 4) & (D_INNER - 1);
    int c = (g >> 15) & (NCHUNK - 1);
    int b = g >> 19;

    float A_en = -__expf(A_log[e * D_STATE + n]);
    float D_e  = D_skip[e];
    size_t rec = (size_t)c * RECSTRIDE + (((size_t)b * D_INNER + e) * D_STATE + n);
    float h = hin[rec];

    const int t0 = c * CHUNK;
    const float* dptr = delta + ((size_t)(b * LL + t0)) * D_INNER + e;
    const float* uptr = u_in  + ((size_t)(b * LL + t0)) * D_INNER + e;
    const float* xdb  = x_dbl + ((size_t)(b * LL + t0)) * 96 + DT_RANK + n;
    const float* zptr = xz    + ((size_t)(b * LL + t0)) * (2 * D_INNER) + D_INNER + e;
    float* yout = ygated + ((size_t)(b * LL + t0)) * D_INNER + e;

    #pragma unroll 4
    for (int t = 0; t < CHUNK; ++t) {
        float dv = dptr[(size_t)t * D_INNER];
        float uv = uptr[(size_t)t * D_INNER];
        float Bv = xdb[t * 96];
        float Cv = xdb[t * 96 + D_STATE];
        float dA = __expf(dv * A_en);
        h = fmaf(dA, h, dv * Bv * uv);
        float part = h * Cv;
        part += __shfl_xor(part, 1);
        part += __shfl_xor(part, 2);
        part += __shfl_xor(part, 4);
        part += __shfl_xor(part, 8);
        if (n == 0) {
            float zv = zptr[(size_t)t * (2 * D_INNER)];
            float yg = (part + uv * D_e) * (zv * sigmoidf_(zv));
            yout[(size_t)t * D_INNER] = yg;
        }
    }
}

// ---------------------------------------------------------------------------
extern "C" void kernel_launch(void* const* d_in, const int* in_sizes, int n_in,
                              void* d_out, int out_size, void* d_ws, size_t ws_size,
                              hipStream_t stream) {
    const float* x      = (const float*)d_in[0];
    const float* W_in   = (const float*)d_in[1];
    const float* conv_w = (const float*)d_in[2];
    const float* conv_b = (const float*)d_in[3];
    const float* W_xp   = (const float*)d_in[4];
    const float* W_dt   = (const float*)d_in[5];
    const float* dt_b   = (const float*)d_in[6];
    const float* A_log  = (const float*)d_in[7];
    const float* D_skip = (const float*)d_in[8];
    const float* W_out  = (const float*)d_in[9];
    float* out = (float*)d_out;

    float* ws     = (float*)d_ws;
    float* xz     = ws;                                    // 8M floats
    float* u      = xz + (size_t)BL * 2 * D_INNER;         // 4M
    float* x_dbl  = u + (size_t)BL * D_INNER;              // 192K
    float* delta  = x_dbl + (size_t)BL * 96;               // 4M
    float* dAprod = delta + (size_t)BL * D_INNER;          // 1M
    float* hend   = dAprod + (size_t)NCHUNK * RECSTRIDE;   // 1M
    float* hin    = hend + (size_t)NCHUNK * RECSTRIDE;     // 1M

    dim3 blk(256);

    // 1) xz = x @ W_in
    {
        dim3 grid(4096 / 64, BL / 64);
        hipLaunchKernelGGL((gemm_f32<0>), grid, blk, 0, stream,
                           x, W_in, xz, nullptr, BL, 2 * D_INNER, D_MODEL,
                           D_MODEL, 2 * D_INNER, 2 * D_INNER);
    }
    // 2) u = silu(convdw(xp) + b)
    {
        int total = BL * D_INNER;
        hipLaunchKernelGGL(conv_silu, dim3((total + 255) / 256), blk, 0, stream,
                           xz, conv_w, conv_b, u);
    }
    // 3) x_dbl = u @ W_xp
    {
        dim3 grid((96 + 63) / 64, BL / 64);
        hipLaunchKernelGGL((gemm_f32<0>), grid, blk, 0, stream,
                           u, W_xp, x_dbl, nullptr, BL, 96, D_INNER,
                           D_INNER, 96, 96);
    }
    // 4) delta = softplus(x_dbl[:, :64] @ W_dt + dt_bias)
    {
        dim3 grid(D_INNER / 64, BL / 64);
        hipLaunchKernelGGL((gemm_f32<1>), grid, blk, 0, stream,
                           x_dbl, W_dt, delta, dt_b, BL, D_INNER, DT_RANK,
                           96, D_INNER, D_INNER);
    }
    // 5) chunked selective scan + gate (ygated in-place over u)
    {
        hipLaunchKernelGGL(scan_phase1, dim3((BB * NCHUNK * D_INNER * D_STATE) / 256),
                           blk, 0, stream, delta, u, x_dbl, A_log, dAprod, hend);
        hipLaunchKernelGGL(scan_phase2, dim3(RECSTRIDE / 256), blk, 0, stream,
                           dAprod, hend, hin);
        hipLaunchKernelGGL(scan_phase3, dim3((BB * NCHUNK * D_INNER * D_STATE) / 256),
                           blk, 0, stream, delta, u, x_dbl, xz, A_log, D_skip, hin, u);
    }
    // 6) out = ygated @ W_out
    {
        dim3 grid(D_MODEL / 64, BL / 64);
        hipLaunchKernelGGL((gemm_f32<0>), grid, blk, 0, stream,
                           u, W_out, out, nullptr, BL, D_MODEL, D_INNER,
                           D_INNER, D_MODEL, D_MODEL);
    }
}

// Round 3
// 475.721 us; speedup vs baseline: 3.0863x; 1.8365x over previous
//
#include <hip/hip_runtime.h>
#include <math.h>

#define D_MODEL 1024
#define D_INNER 2048
#define D_STATE 16
#define D_CONV  4
#define DT_RANK 64
#define BB      2
#define LL      1024
#define BL      (BB*LL)   // 2048 rows (B*L)
#define CHUNK   64
#define NCHUNK  (LL/CHUNK)   // 16
#define RECSTRIDE (BB*D_INNER*D_STATE)   // 65536 records per chunk

typedef __attribute__((ext_vector_type(8))) short short8;
typedef __attribute__((ext_vector_type(4))) float f32x4;
typedef unsigned short ushort_t;
typedef unsigned int uint_t;

__device__ __forceinline__ float sigmoidf_(float x) { return 1.0f / (1.0f + __expf(-x)); }

__device__ __forceinline__ ushort_t f2bf(float f) {
    uint_t u = __float_as_uint(f);
    uint_t r = (u + 0x7fffu + ((u >> 16) & 1u)) >> 16;
    return (ushort_t)r;
}

__device__ __forceinline__ void gload_lds16(const void* g, void* l) {
    __builtin_amdgcn_global_load_lds(
        (const __attribute__((address_space(1))) void*)g,
        (__attribute__((address_space(3))) void*)l,
        16, 0, 0);
}

// ---------------------------------------------------------------------------
// bf16 MFMA GEMM (m97 structure): C[M,N] = A[M,K] @ Bt[N,K]^T, fp32 out.
// Tile 128x128, BK=32, 4 waves (2x2 of 64x64), 16x16x32 MFMA.
// M%128==0, N%128==0, K%32==0.
// ---------------------------------------------------------------------------
__global__ __launch_bounds__(256)
void gemm_bf16(const ushort_t* __restrict__ A, const ushort_t* __restrict__ Bt,
               float* __restrict__ C, int M, int N, int K) {
    __shared__ __align__(16) ushort_t As[128 * 32];
    __shared__ __align__(16) ushort_t Bs[128 * 32];

    const int tid  = threadIdx.x;
    const int lane = tid & 63;
    const int wave = tid >> 6;           // 0..3
    const int wr = wave >> 1, wc = wave & 1;
    const int row0 = blockIdx.y * 128;
    const int col0 = blockIdx.x * 128;

    f32x4 acc[4][4];
    #pragma unroll
    for (int m = 0; m < 4; ++m)
        #pragma unroll
        for (int n = 0; n < 4; ++n)
            acc[m][n] = (f32x4){0.f, 0.f, 0.f, 0.f};

    const ushort_t* Ablk = A  + (size_t)row0 * K;
    const ushort_t* Bblk = Bt + (size_t)col0 * K;
    const int r_ld  = tid >> 2;          // 0..63 row-in-group
    const int c8_ld = (tid & 3) * 8;     // col element offset (8 bf16 = 16B)

    for (int k0 = 0; k0 < K; k0 += 32) {
        #pragma unroll
        for (int i = 0; i < 2; ++i) {
            gload_lds16(Ablk + (size_t)(i * 64 + r_ld) * K + k0 + c8_ld,
                        &As[(i * 64 + wave * 16) * 32]);
            gload_lds16(Bblk + (size_t)(i * 64 + r_ld) * K + k0 + c8_ld,
                        &Bs[(i * 64 + wave * 16) * 32]);
        }
        __syncthreads();   // drains vmcnt -> LDS valid

        short8 af[4], bf[4];
        const int fr = lane & 15;        // fragment row/col
        const int kb = (lane >> 4) * 8;  // k base within BK
        #pragma unroll
        for (int m = 0; m < 4; ++m)
            af[m] = *(const short8*)&As[(wr * 64 + m * 16 + fr) * 32 + kb];
        #pragma unroll
        for (int n = 0; n < 4; ++n)
            bf[n] = *(const short8*)&Bs[(wc * 64 + n * 16 + fr) * 32 + kb];

        #pragma unroll
        for (int m = 0; m < 4; ++m)
            #pragma unroll
            for (int n = 0; n < 4; ++n)
                acc[m][n] = __builtin_amdgcn_mfma_f32_16x16x32_bf16(
                    af[m], bf[n], acc[m][n], 0, 0, 0);
        __syncthreads();   // protect LDS before next stage
    }

    const int crow = (lane >> 4) * 4;
    const int ccol = lane & 15;
    #pragma unroll
    for (int m = 0; m < 4; ++m) {
        #pragma unroll
        for (int n = 0; n < 4; ++n) {
            float* cp = C + (size_t)(row0 + wr * 64 + m * 16 + crow) * N
                          + col0 + wc * 64 + n * 16 + ccol;
            #pragma unroll
            for (int i = 0; i < 4; ++i)
                cp[(size_t)i * N] = acc[m][n][i];
        }
    }
}

// ---------------------------------------------------------------------------
// fp32 -> bf16 elementwise
// ---------------------------------------------------------------------------
__global__ __launch_bounds__(256)
void f32_to_bf16(const float* __restrict__ in, ushort_t* __restrict__ out, int n) {
    int i = (blockIdx.x * 256 + threadIdx.x) * 8;
    if (i + 8 <= n) {
        float4 a = *reinterpret_cast<const float4*>(in + i);
        float4 b = *reinterpret_cast<const float4*>(in + i + 4);
        ushort_t o[8] = {f2bf(a.x), f2bf(a.y), f2bf(a.z), f2bf(a.w),
                         f2bf(b.x), f2bf(b.y), f2bf(b.z), f2bf(b.w)};
        *reinterpret_cast<short8*>(out + i) = *reinterpret_cast<short8*>(o);
    }
}

// ---------------------------------------------------------------------------
// transpose + convert: Wt[c][r] = bf16(W[r][c]).  R%32==0, C%32==0.
// ---------------------------------------------------------------------------
__global__ __launch_bounds__(256)
void transp_bf16(const float* __restrict__ W, ushort_t* __restrict__ Wt,
                 int R, int C) {
    __shared__ ushort_t tile[32][33];
    int tx = threadIdx.x & 31, ty = threadIdx.x >> 5;   // ty 0..7
    int r0 = blockIdx.y * 32, c0 = blockIdx.x * 32;
    #pragma unroll
    for (int i = 0; i < 32; i += 8)
        tile[ty + i][tx] = f2bf(W[(size_t)(r0 + ty + i) * C + c0 + tx]);
    __syncthreads();
    #pragma unroll
    for (int i = 0; i < 32; i += 8)
        Wt[(size_t)(c0 + ty + i) * R + r0 + tx] = tile[tx][ty + i];
}

// ---------------------------------------------------------------------------
// Generic fp32 GEMM (kept for the two small GEMMs).
// EPI==1: C = softplus(acc + bias[col])
// ---------------------------------------------------------------------------
template<int EPI>
__global__ __launch_bounds__(256)
void gemm_f32(const float* __restrict__ A, const float* __restrict__ B,
              float* __restrict__ C, const float* __restrict__ bias,
              int M, int N, int K, int lda, int ldb, int ldc) {
    __shared__ float As[16][65];
    __shared__ float Bs[16][64];

    const int tid = threadIdx.x;
    const int tx = tid & 15;
    const int ty = tid >> 4;
    const int row0 = blockIdx.y * 64;
    const int col0 = blockIdx.x * 64;

    const int arow = tid >> 4;
    const int acol = tid & 15;
    const int brow = tid >> 6;
    const int bcol = tid & 63;

    float acc[4][4] = {};

    for (int k0 = 0; k0 < K; k0 += 16) {
        #pragma unroll
        for (int p = 0; p < 4; ++p) {
            int r = arow + p * 16;
            As[acol][r] = A[(size_t)(row0 + r) * lda + (k0 + acol)];
        }
        int gc = col0 + bcol;
        #pragma unroll
        for (int p = 0; p < 4; ++p) {
            int r = brow + p * 4;
            Bs[r][bcol] = (gc < N) ? B[(size_t)(k0 + r) * ldb + gc] : 0.0f;
        }
        __syncthreads();
        #pragma unroll
        for (int kk = 0; kk < 16; ++kk) {
            float a[4];
            #pragma unroll
            for (int i = 0; i < 4; ++i) a[i] = As[kk][ty * 4 + i];
            float4 bv = *reinterpret_cast<const float4*>(&Bs[kk][tx * 4]);
            float b4[4] = {bv.x, bv.y, bv.z, bv.w};
            #pragma unroll
            for (int i = 0; i < 4; ++i)
                #pragma unroll
                for (int j = 0; j < 4; ++j)
                    acc[i][j] = fmaf(a[i], b4[j], acc[i][j]);
        }
        __syncthreads();
    }

    #pragma unroll
    for (int i = 0; i < 4; ++i) {
        int gr = row0 + ty * 4 + i;
        #pragma unroll
        for (int j = 0; j < 4; ++j) {
            int gc = col0 + tx * 4 + j;
            if (gc < N) {
                float v = acc[i][j];
                if (EPI == 1) {
                    v += bias[gc];
                    v = (v > 20.0f) ? v : log1pf(__expf(v));
                }
                C[(size_t)gr * ldc + gc] = v;
            }
        }
    }
}

// ---------------------------------------------------------------------------
// Causal depthwise conv (K=4) + bias + SiLU.
// ---------------------------------------------------------------------------
__global__ __launch_bounds__(256)
void conv_silu(const float* __restrict__ xz, const float* __restrict__ conv_w,
               const float* __restrict__ conv_b, float* __restrict__ u) {
    int idx = blockIdx.x * 256 + threadIdx.x;
    if (idx >= BL * D_INNER) return;
    int e  = idx & (D_INNER - 1);
    int bl = idx >> 11;
    int b = bl >> 10, l = bl & (LL - 1);
    float acc = conv_b[e];
    #pragma unroll
    for (int k = 0; k < D_CONV; ++k) {
        int ll = l - (D_CONV - 1) + k;
        if (ll >= 0)
            acc = fmaf(conv_w[e * D_CONV + k],
                       xz[(size_t)(b * LL + ll) * (2 * D_INNER) + e], acc);
    }
    u[idx] = acc * sigmoidf_(acc);
}

// ---------------------------------------------------------------------------
// Chunked selective scan (3 phases).
// ---------------------------------------------------------------------------
__global__ __launch_bounds__(256)
void scan_phase1(const float* __restrict__ delta, const float* __restrict__ u_in,
                 const float* __restrict__ x_dbl, const float* __restrict__ A_log,
                 float* __restrict__ dAprod, float* __restrict__ hend) {
    int g = blockIdx.x * 256 + threadIdx.x;
    int n = g & 15;
    int e = (g >> 4) & (D_INNER - 1);
    int c = (g >> 15) & (NCHUNK - 1);
    int b = g >> 19;

    float A_en = -__expf(A_log[e * D_STATE + n]);
    float h = 0.0f, P = 1.0f;
    const int t0 = c * CHUNK;
    const float* dptr = delta + ((size_t)(b * LL + t0)) * D_INNER + e;
    const float* uptr = u_in  + ((size_t)(b * LL + t0)) * D_INNER + e;
    const float* xdb  = x_dbl + ((size_t)(b * LL + t0)) * 96 + DT_RANK + n;

    #pragma unroll 4
    for (int t = 0; t < CHUNK; ++t) {
        float dv = dptr[(size_t)t * D_INNER];
        float uv = uptr[(size_t)t * D_INNER];
        float Bv = xdb[t * 96];
        float dA = __expf(dv * A_en);
        h = fmaf(dA, h, dv * Bv * uv);
        P *= dA;
    }
    size_t rec = (size_t)c * RECSTRIDE + (((size_t)b * D_INNER + e) * D_STATE + n);
    dAprod[rec] = P;
    hend[rec] = h;
}

__global__ __launch_bounds__(256)
void scan_phase2(const float* __restrict__ dAprod, const float* __restrict__ hend,
                 float* __restrict__ hin) {
    int g = blockIdx.x * 256 + threadIdx.x;
    float h = 0.0f;
    #pragma unroll
    for (int c = 0; c < NCHUNK; ++c) {
        size_t rec = (size_t)c * RECSTRIDE + g;
        hin[rec] = h;
        h = fmaf(dAprod[rec], h, hend[rec]);
    }
}

__global__ __launch_bounds__(256)
void scan_phase3(const float* __restrict__ delta, const float* __restrict__ u_in,
                 const float* __restrict__ x_dbl, const float* __restrict__ xz,
                 const float* __restrict__ A_log, const float* __restrict__ D_skip,
                 const float* __restrict__ hin, ushort_t* __restrict__ ybf) {
    int g = blockIdx.x * 256 + threadIdx.x;
    int n = g & 15;
    int e = (g >> 4) & (D_INNER - 1);
    int c = (g >> 15) & (NCHUNK - 1);
    int b = g >> 19;

    float A_en = -__expf(A_log[e * D_STATE + n]);
    float D_e  = D_skip[e];
    size_t rec = (size_t)c * RECSTRIDE + (((size_t)b * D_INNER + e) * D_STATE + n);
    float h = hin[rec];

    const int t0 = c * CHUNK;
    const float* dptr = delta + ((size_t)(b * LL + t0)) * D_INNER + e;
    const float* uptr = u_in  + ((size_t)(b * LL + t0)) * D_INNER + e;
    const float* xdb  = x_dbl + ((size_t)(b * LL + t0)) * 96 + DT_RANK + n;
    const float* zptr = xz    + ((size_t)(b * LL + t0)) * (2 * D_INNER) + D_INNER + e;
    ushort_t* yout = ybf + ((size_t)(b * LL + t0)) * D_INNER + e;

    #pragma unroll 4
    for (int t = 0; t < CHUNK; ++t) {
        float dv = dptr[(size_t)t * D_INNER];
        float uv = uptr[(size_t)t * D_INNER];
        float Bv = xdb[t * 96];
        float Cv = xdb[t * 96 + D_STATE];
        float dA = __expf(dv * A_en);
        h = fmaf(dA, h, dv * Bv * uv);
        float part = h * Cv;
        part += __shfl_xor(part, 1);
        part += __shfl_xor(part, 2);
        part += __shfl_xor(part, 4);
        part += __shfl_xor(part, 8);
        if (n == 0) {
            float zv = zptr[(size_t)t * (2 * D_INNER)];
            float yg = (part + uv * D_e) * (zv * sigmoidf_(zv));
            yout[(size_t)t * D_INNER] = f2bf(yg);
        }
    }
}

// ---------------------------------------------------------------------------
extern "C" void kernel_launch(void* const* d_in, const int* in_sizes, int n_in,
                              void* d_out, int out_size, void* d_ws, size_t ws_size,
                              hipStream_t stream) {
    const float* x      = (const float*)d_in[0];
    const float* W_in   = (const float*)d_in[1];
    const float* conv_w = (const float*)d_in[2];
    const float* conv_b = (const float*)d_in[3];
    const float* W_xp   = (const float*)d_in[4];
    const float* W_dt   = (const float*)d_in[5];
    const float* dt_b   = (const float*)d_in[6];
    const float* A_log  = (const float*)d_in[7];
    const float* D_skip = (const float*)d_in[8];
    const float* W_out  = (const float*)d_in[9];
    float* out = (float*)d_out;

    // workspace layout (floats) — 19.2M floats total (same as proven round 2)
    float* ws     = (float*)d_ws;
    float* xz     = ws;                                    // 8M
    float* u      = xz + (size_t)BL * 2 * D_INNER;         // 4M
    float* x_dbl  = u + (size_t)BL * D_INNER;              // 192K
    float* delta  = x_dbl + (size_t)BL * 96;               // 4M
    float* dAprod = delta + (size_t)BL * D_INNER;          // 1M
    float* hend   = dAprod + (size_t)NCHUNK * RECSTRIDE;   // 1M
    float* hin    = hend + (size_t)NCHUNK * RECSTRIDE;     // 1M

    // bf16 aliases (time-disjoint with their hosts):
    ushort_t* x_bf     = (ushort_t*)delta;                 // 2M bf16 (used step 1 only; delta written step 4)
    ushort_t* Wint_bf  = (ushort_t*)(delta + 1024 * 1024); // 4M bf16 (used step 1 only)
    ushort_t* Woutt_bf = (ushort_t*)(delta + 3 * 1024 * 1024); // 2M bf16 (written after phase3, delta dead)
    ushort_t* ybf      = (ushort_t*)dAprod;                // 4M bf16 (phase3 out; dAprod/hend dead after phase2)

    dim3 blk(256);

    // 0a) x -> bf16
    hipLaunchKernelGGL(f32_to_bf16, dim3((BL * D_MODEL) / (256 * 8)), blk, 0, stream,
                       x, x_bf, BL * D_MODEL);
    // 0b) W_in [1024,4096] -> Wint_bf [4096,1024]
    hipLaunchKernelGGL(transp_bf16, dim3(4096 / 32, 1024 / 32), blk, 0, stream,
                       W_in, Wint_bf, 1024, 4096);
    // 1) xz = x @ W_in   (bf16 MFMA)
    hipLaunchKernelGGL(gemm_bf16, dim3(4096 / 128, BL / 128), blk, 0, stream,
                       x_bf, Wint_bf, xz, BL, 2 * D_INNER, D_MODEL);
    // 2) u = silu(convdw(xp) + b)
    hipLaunchKernelGGL(conv_silu, dim3((BL * D_INNER) / 256), blk, 0, stream,
                       xz, conv_w, conv_b, u);
    // 3) x_dbl = u @ W_xp   (fp32)
    hipLaunchKernelGGL((gemm_f32<0>), dim3((96 + 63) / 64, BL / 64), blk, 0, stream,
                       u, W_xp, x_dbl, nullptr, BL, 96, D_INNER, D_INNER, 96, 96);
    // 4) delta = softplus(x_dbl[:, :64] @ W_dt + dt_bias)   (fp32)
    hipLaunchKernelGGL((gemm_f32<1>), dim3(D_INNER / 64, BL / 64), blk, 0, stream,
                       x_dbl, W_dt, delta, dt_b, BL, D_INNER, DT_RANK, 96, D_INNER, D_INNER);
    // 5) chunked selective scan + gate -> ybf (bf16)
    hipLaunchKernelGGL(scan_phase1, dim3((BB * NCHUNK * D_INNER * D_STATE) / 256),
                       blk, 0, stream, delta, u, x_dbl, A_log, dAprod, hend);
    hipLaunchKernelGGL(scan_phase2, dim3(RECSTRIDE / 256), blk, 0, stream,
                       dAprod, hend, hin);
    hipLaunchKernelGGL(scan_phase3, dim3((BB * NCHUNK * D_INNER * D_STATE) / 256),
                       blk, 0, stream, delta, u, x_dbl, xz, A_log, D_skip, hin, ybf);
    // 5b) W_out [2048,1024] -> Woutt_bf [1024,2048]  (delta region now dead)
    hipLaunchKernelGGL(transp_bf16, dim3(1024 / 32, 2048 / 32), blk, 0, stream,
                       W_out, Woutt_bf, 2048, 1024);
    // 6) out = ybf @ W_out   (bf16 MFMA)
    hipLaunchKernelGGL(gemm_bf16, dim3(D_MODEL / 128, BL / 128), blk, 0, stream,
                       ybf, Woutt_bf, out, BL, D_MODEL, D_INNER);
}

// Round 4
// 306.619 us; speedup vs baseline: 4.7884x; 1.5515x over previous
//
#include <hip/hip_runtime.h>
#include <math.h>

#define D_MODEL 1024
#define D_INNER 2048
#define D_STATE 16
#define D_CONV  4
#define DT_RANK 64
#define BB      2
#define LL      1024
#define BL      (BB*LL)   // 2048 rows (B*L)
#define CHUNK   64
#define NCHUNK  (LL/CHUNK)   // 16
#define RECSTRIDE (BB*D_INNER*D_STATE)   // 65536 records per chunk
#define KSPLIT  16           // split-K for x_dbl GEMM

typedef __attribute__((ext_vector_type(8))) short short8;
typedef __attribute__((ext_vector_type(4))) float f32x4;
typedef unsigned short ushort_t;
typedef unsigned int uint_t;

__device__ __forceinline__ float sigmoidf_(float x) { return 1.0f / (1.0f + __expf(-x)); }

__device__ __forceinline__ ushort_t f2bf(float f) {
    uint_t u = __float_as_uint(f);
    uint_t r = (u + 0x7fffu + ((u >> 16) & 1u)) >> 16;
    return (ushort_t)r;
}

__device__ __forceinline__ void gload_lds16(const void* g, void* l) {
    __builtin_amdgcn_global_load_lds(
        (const __attribute__((address_space(1))) void*)g,
        (__attribute__((address_space(3))) void*)l,
        16, 0, 0);
}

// ---------------------------------------------------------------------------
// bf16 MFMA GEMM (m97 structure): C[M,N] = A[M,K] @ Bt[N,K]^T, fp32 out.
// Tile 128x128, BK=32, 4 waves (2x2 of 64x64), 16x16x32 MFMA.
// ---------------------------------------------------------------------------
__global__ __launch_bounds__(256)
void gemm_bf16(const ushort_t* __restrict__ A, const ushort_t* __restrict__ Bt,
               float* __restrict__ C, int M, int N, int K) {
    __shared__ __align__(16) ushort_t As[128 * 32];
    __shared__ __align__(16) ushort_t Bs[128 * 32];

    const int tid  = threadIdx.x;
    const int lane = tid & 63;
    const int wave = tid >> 6;
    const int wr = wave >> 1, wc = wave & 1;
    const int row0 = blockIdx.y * 128;
    const int col0 = blockIdx.x * 128;

    f32x4 acc[4][4];
    #pragma unroll
    for (int m = 0; m < 4; ++m)
        #pragma unroll
        for (int n = 0; n < 4; ++n)
            acc[m][n] = (f32x4){0.f, 0.f, 0.f, 0.f};

    const ushort_t* Ablk = A  + (size_t)row0 * K;
    const ushort_t* Bblk = Bt + (size_t)col0 * K;
    const int r_ld  = tid >> 2;
    const int c8_ld = (tid & 3) * 8;

    for (int k0 = 0; k0 < K; k0 += 32) {
        #pragma unroll
        for (int i = 0; i < 2; ++i) {
            gload_lds16(Ablk + (size_t)(i * 64 + r_ld) * K + k0 + c8_ld,
                        &As[(i * 64 + wave * 16) * 32]);
            gload_lds16(Bblk + (size_t)(i * 64 + r_ld) * K + k0 + c8_ld,
                        &Bs[(i * 64 + wave * 16) * 32]);
        }
        __syncthreads();

        short8 af[4], bf[4];
        const int fr = lane & 15;
        const int kb = (lane >> 4) * 8;
        #pragma unroll
        for (int m = 0; m < 4; ++m)
            af[m] = *(const short8*)&As[(wr * 64 + m * 16 + fr) * 32 + kb];
        #pragma unroll
        for (int n = 0; n < 4; ++n)
            bf[n] = *(const short8*)&Bs[(wc * 64 + n * 16 + fr) * 32 + kb];

        #pragma unroll
        for (int m = 0; m < 4; ++m)
            #pragma unroll
            for (int n = 0; n < 4; ++n)
                acc[m][n] = __builtin_amdgcn_mfma_f32_16x16x32_bf16(
                    af[m], bf[n], acc[m][n], 0, 0, 0);
        __syncthreads();
    }

    const int crow = (lane >> 4) * 4;
    const int ccol = lane & 15;
    #pragma unroll
    for (int m = 0; m < 4; ++m) {
        #pragma unroll
        for (int n = 0; n < 4; ++n) {
            float* cp = C + (size_t)(row0 + wr * 64 + m * 16 + crow) * N
                          + col0 + wc * 64 + n * 16 + ccol;
            #pragma unroll
            for (int i = 0; i < 4; ++i)
                cp[(size_t)i * N] = acc[m][n][i];
        }
    }
}

// ---------------------------------------------------------------------------
// fp32 -> bf16 elementwise
// ---------------------------------------------------------------------------
__global__ __launch_bounds__(256)
void f32_to_bf16(const float* __restrict__ in, ushort_t* __restrict__ out, int n) {
    int i = (blockIdx.x * 256 + threadIdx.x) * 8;
    if (i + 8 <= n) {
        float4 a = *reinterpret_cast<const float4*>(in + i);
        float4 b = *reinterpret_cast<const float4*>(in + i + 4);
        ushort_t o[8] = {f2bf(a.x), f2bf(a.y), f2bf(a.z), f2bf(a.w),
                         f2bf(b.x), f2bf(b.y), f2bf(b.z), f2bf(b.w)};
        *reinterpret_cast<short8*>(out + i) = *reinterpret_cast<short8*>(o);
    }
}

// ---------------------------------------------------------------------------
// transpose + convert: Wt[c][r] = bf16(W[r][c]).
// ---------------------------------------------------------------------------
__global__ __launch_bounds__(256)
void transp_bf16(const float* __restrict__ W, ushort_t* __restrict__ Wt,
                 int R, int C) {
    __shared__ ushort_t tile[32][33];
    int tx = threadIdx.x & 31, ty = threadIdx.x >> 5;
    int r0 = blockIdx.y * 32, c0 = blockIdx.x * 32;
    #pragma unroll
    for (int i = 0; i < 32; i += 8)
        tile[ty + i][tx] = f2bf(W[(size_t)(r0 + ty + i) * C + c0 + tx]);
    __syncthreads();
    #pragma unroll
    for (int i = 0; i < 32; i += 8)
        Wt[(size_t)(c0 + ty + i) * R + r0 + tx] = tile[tx][ty + i];
}

// ---------------------------------------------------------------------------
// Split-K GEMM for x_dbl: part[s] = u[:, s*128:(s+1)*128] @ W_xp[s*128.., :]
// Tile: 64 rows x 96 cols x K=128 per block. grid (32, KSPLIT).
// ---------------------------------------------------------------------------
__global__ __launch_bounds__(256)
void gemm_xdbl_splitk(const float* __restrict__ u, const float* __restrict__ W,
                      float* __restrict__ part) {
    __shared__ float As[16][65];
    __shared__ float Bs[16][96];

    const int tid = threadIdx.x;
    const int m0 = blockIdx.x * 64;
    const int kbase = blockIdx.y * (D_INNER / KSPLIT);   // *128

    const int tx = tid & 15;       // col group: cols tx*6 .. tx*6+5
    const int ty = tid >> 4;       // row group: rows ty*4 .. ty*4+3
    const int arow = tid >> 4;
    const int acol = tid & 15;

    float acc[4][6] = {};

    for (int k0 = 0; k0 < D_INNER / KSPLIT; k0 += 16) {
        #pragma unroll
        for (int p = 0; p < 4; ++p) {
            int r = arow + p * 16;
            As[acol][r] = u[(size_t)(m0 + r) * D_INNER + kbase + k0 + acol];
        }
        #pragma unroll
        for (int j = 0; j < 6; ++j) {
            int idx = j * 256 + tid;            // 0..1535
            int row = idx / 96, col = idx - row * 96;
            Bs[row][col] = W[(size_t)(kbase + k0 + row) * 96 + col];
        }
        __syncthreads();
        #pragma unroll
        for (int kk = 0; kk < 16; ++kk) {
            float a[4], b[6];
            #pragma unroll
            for (int i = 0; i < 4; ++i) a[i] = As[kk][ty * 4 + i];
            #pragma unroll
            for (int j = 0; j < 6; ++j) b[j] = Bs[kk][tx * 6 + j];
            #pragma unroll
            for (int i = 0; i < 4; ++i)
                #pragma unroll
                for (int j = 0; j < 6; ++j)
                    acc[i][j] = fmaf(a[i], b[j], acc[i][j]);
        }
        __syncthreads();
    }

    float* pblk = part + (size_t)blockIdx.y * BL * 96;
    #pragma unroll
    for (int i = 0; i < 4; ++i)
        #pragma unroll
        for (int j = 0; j < 6; ++j)
            pblk[(size_t)(m0 + ty * 4 + i) * 96 + tx * 6 + j] = acc[i][j];
}

__global__ __launch_bounds__(256)
void xdbl_reduce(const float* __restrict__ part, float* __restrict__ x_dbl) {
    int i = blockIdx.x * 256 + threadIdx.x;     // < 2048*96
    float s = 0.0f;
    #pragma unroll
    for (int k = 0; k < KSPLIT; ++k)
        s += part[(size_t)k * BL * 96 + i];
    x_dbl[i] = s;
}

// ---------------------------------------------------------------------------
// Generic fp32 GEMM (still used for delta).
// EPI==1: C = softplus(acc + bias[col])
// ---------------------------------------------------------------------------
template<int EPI>
__global__ __launch_bounds__(256)
void gemm_f32(const float* __restrict__ A, const float* __restrict__ B,
              float* __restrict__ C, const float* __restrict__ bias,
              int M, int N, int K, int lda, int ldb, int ldc) {
    __shared__ float As[16][65];
    __shared__ float Bs[16][64];

    const int tid = threadIdx.x;
    const int tx = tid & 15;
    const int ty = tid >> 4;
    const int row0 = blockIdx.y * 64;
    const int col0 = blockIdx.x * 64;

    const int arow = tid >> 4;
    const int acol = tid & 15;
    const int brow = tid >> 6;
    const int bcol = tid & 63;

    float acc[4][4] = {};

    for (int k0 = 0; k0 < K; k0 += 16) {
        #pragma unroll
        for (int p = 0; p < 4; ++p) {
            int r = arow + p * 16;
            As[acol][r] = A[(size_t)(row0 + r) * lda + (k0 + acol)];
        }
        int gc = col0 + bcol;
        #pragma unroll
        for (int p = 0; p < 4; ++p) {
            int r = brow + p * 4;
            Bs[r][bcol] = (gc < N) ? B[(size_t)(k0 + r) * ldb + gc] : 0.0f;
        }
        __syncthreads();
        #pragma unroll
        for (int kk = 0; kk < 16; ++kk) {
            float a[4];
            #pragma unroll
            for (int i = 0; i < 4; ++i) a[i] = As[kk][ty * 4 + i];
            float4 bv = *reinterpret_cast<const float4*>(&Bs[kk][tx * 4]);
            float b4[4] = {bv.x, bv.y, bv.z, bv.w};
            #pragma unroll
            for (int i = 0; i < 4; ++i)
                #pragma unroll
                for (int j = 0; j < 4; ++j)
                    acc[i][j] = fmaf(a[i], b4[j], acc[i][j]);
        }
        __syncthreads();
    }

    #pragma unroll
    for (int i = 0; i < 4; ++i) {
        int gr = row0 + ty * 4 + i;
        #pragma unroll
        for (int j = 0; j < 4; ++j) {
            int gc = col0 + tx * 4 + j;
            if (gc < N) {
                float v = acc[i][j];
                if (EPI == 1) {
                    v += bias[gc];
                    v = (v > 20.0f) ? v : log1pf(__expf(v));
                }
                C[(size_t)gr * ldc + gc] = v;
            }
        }
    }
}

// ---------------------------------------------------------------------------
// Causal depthwise conv (K=4) + bias + SiLU.
// ---------------------------------------------------------------------------
__global__ __launch_bounds__(256)
void conv_silu(const float* __restrict__ xz, const float* __restrict__ conv_w,
               const float* __restrict__ conv_b, float* __restrict__ u) {
    int idx = blockIdx.x * 256 + threadIdx.x;
    if (idx >= BL * D_INNER) return;
    int e  = idx & (D_INNER - 1);
    int bl = idx >> 11;
    int b = bl >> 10, l = bl & (LL - 1);
    float acc = conv_b[e];
    #pragma unroll
    for (int k = 0; k < D_CONV; ++k) {
        int ll = l - (D_CONV - 1) + k;
        if (ll >= 0)
            acc = fmaf(conv_w[e * D_CONV + k],
                       xz[(size_t)(b * LL + ll) * (2 * D_INNER) + e], acc);
    }
    u[idx] = acc * sigmoidf_(acc);
}

// ---------------------------------------------------------------------------
// Chunked selective scan (3 phases).
// ---------------------------------------------------------------------------
__global__ __launch_bounds__(256)
void scan_phase1(const float* __restrict__ delta, const float* __restrict__ u_in,
                 const float* __restrict__ x_dbl, const float* __restrict__ A_log,
                 float* __restrict__ dAprod, float* __restrict__ hend) {
    int g = blockIdx.x * 256 + threadIdx.x;
    int n = g & 15;
    int e = (g >> 4) & (D_INNER - 1);
    int c = (g >> 15) & (NCHUNK - 1);
    int b = g >> 19;

    float A_en = -__expf(A_log[e * D_STATE + n]);
    float h = 0.0f, P = 1.0f;
    const int t0 = c * CHUNK;
    const float* dptr = delta + ((size_t)(b * LL + t0)) * D_INNER + e;
    const float* uptr = u_in  + ((size_t)(b * LL + t0)) * D_INNER + e;
    const float* xdb  = x_dbl + ((size_t)(b * LL + t0)) * 96 + DT_RANK + n;

    #pragma unroll 4
    for (int t = 0; t < CHUNK; ++t) {
        float dv = dptr[(size_t)t * D_INNER];
        float uv = uptr[(size_t)t * D_INNER];
        float Bv = xdb[t * 96];
        float dA = __expf(dv * A_en);
        h = fmaf(dA, h, dv * Bv * uv);
        P *= dA;
    }
    size_t rec = (size_t)c * RECSTRIDE + (((size_t)b * D_INNER + e) * D_STATE + n);
    dAprod[rec] = P;
    hend[rec] = h;
}

__global__ __launch_bounds__(256)
void scan_phase2(const float* __restrict__ dAprod, const float* __restrict__ hend,
                 float* __restrict__ hin) {
    int g = blockIdx.x * 256 + threadIdx.x;
    float h = 0.0f;
    #pragma unroll
    for (int c = 0; c < NCHUNK; ++c) {
        size_t rec = (size_t)c * RECSTRIDE + g;
        hin[rec] = h;
        h = fmaf(dAprod[rec], h, hend[rec]);
    }
}

__global__ __launch_bounds__(256)
void scan_phase3(const float* __restrict__ delta, const float* __restrict__ u_in,
                 const float* __restrict__ x_dbl, const float* __restrict__ xz,
                 const float* __restrict__ A_log, const float* __restrict__ D_skip,
                 const float* __restrict__ hin, ushort_t* __restrict__ ybf) {
    int g = blockIdx.x * 256 + threadIdx.x;
    int n = g & 15;
    int e = (g >> 4) & (D_INNER - 1);
    int c = (g >> 15) & (NCHUNK - 1);
    int b = g >> 19;

    float A_en = -__expf(A_log[e * D_STATE + n]);
    float D_e  = D_skip[e];
    size_t rec = (size_t)c * RECSTRIDE + (((size_t)b * D_INNER + e) * D_STATE + n);
    float h = hin[rec];

    const int t0 = c * CHUNK;
    const float* dptr = delta + ((size_t)(b * LL + t0)) * D_INNER + e;
    const float* uptr = u_in  + ((size_t)(b * LL + t0)) * D_INNER + e;
    const float* xdb  = x_dbl + ((size_t)(b * LL + t0)) * 96 + DT_RANK + n;
    const float* zptr = xz    + ((size_t)(b * LL + t0)) * (2 * D_INNER) + D_INNER + e;
    ushort_t* yout = ybf + ((size_t)(b * LL + t0)) * D_INNER + e;

    #pragma unroll 4
    for (int t = 0; t < CHUNK; ++t) {
        float dv = dptr[(size_t)t * D_INNER];
        float uv = uptr[(size_t)t * D_INNER];
        float Bv = xdb[t * 96];
        float Cv = xdb[t * 96 + D_STATE];
        float dA = __expf(dv * A_en);
        h = fmaf(dA, h, dv * Bv * uv);
        float part = h * Cv;
        part += __shfl_xor(part, 1);
        part += __shfl_xor(part, 2);
        part += __shfl_xor(part, 4);
        part += __shfl_xor(part, 8);
        if (n == 0) {
            float zv = zptr[(size_t)t * (2 * D_INNER)];
            float yg = (part + uv * D_e) * (zv * sigmoidf_(zv));
            yout[(size_t)t * D_INNER] = f2bf(yg);
        }
    }
}

// ---------------------------------------------------------------------------
extern "C" void kernel_launch(void* const* d_in, const int* in_sizes, int n_in,
                              void* d_out, int out_size, void* d_ws, size_t ws_size,
                              hipStream_t stream) {
    const float* x      = (const float*)d_in[0];
    const float* W_in   = (const float*)d_in[1];
    const float* conv_w = (const float*)d_in[2];
    const float* conv_b = (const float*)d_in[3];
    const float* W_xp   = (const float*)d_in[4];
    const float* W_dt   = (const float*)d_in[5];
    const float* dt_b   = (const float*)d_in[6];
    const float* A_log  = (const float*)d_in[7];
    const float* D_skip = (const float*)d_in[8];
    const float* W_out  = (const float*)d_in[9];
    float* out = (float*)d_out;

    // workspace layout (floats) — 19.2M floats total
    float* ws     = (float*)d_ws;
    float* xz     = ws;                                    // 8M
    float* u      = xz + (size_t)BL * 2 * D_INNER;         // 4M
    float* x_dbl  = u + (size_t)BL * D_INNER;              // 192K
    float* delta  = x_dbl + (size_t)BL * 96;               // 4M
    float* dAprod = delta + (size_t)BL * D_INNER;          // 1M
    float* hend   = dAprod + (size_t)NCHUNK * RECSTRIDE;   // 1M
    float* hin    = hend + (size_t)NCHUNK * RECSTRIDE;     // 1M

    // time-disjoint aliases in the delta region (4M floats):
    ushort_t* x_bf     = (ushort_t*)delta;                 // steps 0a..1
    ushort_t* Wint_bf  = (ushort_t*)(delta + 1024 * 1024); // steps 0b..1
    float*    xdbl_part= delta;                            // step 3 (3.07M floats), dead before step 4
    ushort_t* Woutt_bf = (ushort_t*)(delta + 3 * 1024 * 1024); // steps 5b..6 (delta dead)
    ushort_t* ybf      = (ushort_t*)dAprod;                // phase3 out (dAprod/hend dead)

    dim3 blk(256);

    // 0a) x -> bf16
    hipLaunchKernelGGL(f32_to_bf16, dim3((BL * D_MODEL) / (256 * 8)), blk, 0, stream,
                       x, x_bf, BL * D_MODEL);
    // 0b) W_in [1024,4096] -> Wint_bf [4096,1024]
    hipLaunchKernelGGL(transp_bf16, dim3(4096 / 32, 1024 / 32), blk, 0, stream,
                       W_in, Wint_bf, 1024, 4096);
    // 1) xz = x @ W_in   (bf16 MFMA)
    hipLaunchKernelGGL(gemm_bf16, dim3(4096 / 128, BL / 128), blk, 0, stream,
                       x_bf, Wint_bf, xz, BL, 2 * D_INNER, D_MODEL);
    // 2) u = silu(convdw(xp) + b)
    hipLaunchKernelGGL(conv_silu, dim3((BL * D_INNER) / 256), blk, 0, stream,
                       xz, conv_w, conv_b, u);
    // 3) x_dbl = u @ W_xp   (fp32 split-K; x_bf/Wint_bf dead now)
    hipLaunchKernelGGL(gemm_xdbl_splitk, dim3(BL / 64, KSPLIT), blk, 0, stream,
                       u, W_xp, xdbl_part);
    hipLaunchKernelGGL(xdbl_reduce, dim3((BL * 96) / 256), blk, 0, stream,
                       xdbl_part, x_dbl);
    // 4) delta = softplus(x_dbl[:, :64] @ W_dt + dt_bias)   (fp32; overwrites xdbl_part)
    hipLaunchKernelGGL((gemm_f32<1>), dim3(D_INNER / 64, BL / 64), blk, 0, stream,
                       x_dbl, W_dt, delta, dt_b, BL, D_INNER, DT_RANK, 96, D_INNER, D_INNER);
    // 5) chunked selective scan + gate -> ybf (bf16)
    hipLaunchKernelGGL(scan_phase1, dim3((BB * NCHUNK * D_INNER * D_STATE) / 256),
                       blk, 0, stream, delta, u, x_dbl, A_log, dAprod, hend);
    hipLaunchKernelGGL(scan_phase2, dim3(RECSTRIDE / 256), blk, 0, stream,
                       dAprod, hend, hin);
    hipLaunchKernelGGL(scan_phase3, dim3((BB * NCHUNK * D_INNER * D_STATE) / 256),
                       blk, 0, stream, delta, u, x_dbl, xz, A_log, D_skip, hin, ybf);
    // 5b) W_out [2048,1024] -> Woutt_bf [1024,2048]  (delta dead)
    hipLaunchKernelGGL(transp_bf16, dim3(1024 / 32, 2048 / 32), blk, 0, stream,
                       W_out, Woutt_bf, 2048, 1024);
    // 6) out = ybf @ W_out   (bf16 MFMA)
    hipLaunchKernelGGL(gemm_bf16, dim3(D_MODEL / 128, BL / 128), blk, 0, stream,
                       ybf, Woutt_bf, out, BL, D_MODEL, D_INNER);
}

// Round 5
// 215.148 us; speedup vs baseline: 6.8241x; 1.4252x over previous
//
#include <hip/hip_runtime.h>
#include <math.h>

#define D_MODEL 1024
#define D_INNER 2048
#define D_STATE 16
#define D_CONV  4
#define DT_RANK 64
#define BB      2
#define LL      1024
#define BL      (BB*LL)   // 2048 rows (B*L)
#define CHUNK   16
#define NCHUNK  (LL/CHUNK)   // 64
#define KSPLIT  16           // split-K for x_dbl GEMM

typedef __attribute__((ext_vector_type(8))) short short8;
typedef __attribute__((ext_vector_type(4))) float f32x4;
typedef unsigned short ushort_t;
typedef unsigned int uint_t;

__device__ __forceinline__ float sigmoidf_(float x) { return 1.0f / (1.0f + __expf(-x)); }

__device__ __forceinline__ ushort_t f2bf(float f) {
    uint_t u = __float_as_uint(f);
    uint_t r = (u + 0x7fffu + ((u >> 16) & 1u)) >> 16;
    return (ushort_t)r;
}

__device__ __forceinline__ void gload_lds16(const void* g, void* l) {
    __builtin_amdgcn_global_load_lds(
        (const __attribute__((address_space(1))) void*)g,
        (__attribute__((address_space(3))) void*)l,
        16, 0, 0);
}

// ---------------------------------------------------------------------------
// bf16 MFMA GEMM: C = A[M,K] @ Bt[N,K]^T, fp32 out, column-split epilogue:
// cols [0,split) -> C0 (ldc=split), cols [split,N) -> C1 (ldc=N-split).
// Tile 128x128, BK=32, 4 waves, 16x16x32 MFMA. split % 128 == 0.
// ---------------------------------------------------------------------------
__global__ __launch_bounds__(256)
void gemm_bf16(const ushort_t* __restrict__ A, const ushort_t* __restrict__ Bt,
               float* __restrict__ C0, float* __restrict__ C1,
               int M, int N, int K, int split) {
    __shared__ __align__(16) ushort_t As[128 * 32];
    __shared__ __align__(16) ushort_t Bs[128 * 32];

    const int tid  = threadIdx.x;
    const int lane = tid & 63;
    const int wave = tid >> 6;
    const int wr = wave >> 1, wc = wave & 1;
    const int row0 = blockIdx.y * 128;
    const int col0 = blockIdx.x * 128;

    f32x4 acc[4][4];
    #pragma unroll
    for (int m = 0; m < 4; ++m)
        #pragma unroll
        for (int n = 0; n < 4; ++n)
            acc[m][n] = (f32x4){0.f, 0.f, 0.f, 0.f};

    const ushort_t* Ablk = A  + (size_t)row0 * K;
    const ushort_t* Bblk = Bt + (size_t)col0 * K;
    const int r_ld  = tid >> 2;
    const int c8_ld = (tid & 3) * 8;

    for (int k0 = 0; k0 < K; k0 += 32) {
        #pragma unroll
        for (int i = 0; i < 2; ++i) {
            gload_lds16(Ablk + (size_t)(i * 64 + r_ld) * K + k0 + c8_ld,
                        &As[(i * 64 + wave * 16) * 32]);
            gload_lds16(Bblk + (size_t)(i * 64 + r_ld) * K + k0 + c8_ld,
                        &Bs[(i * 64 + wave * 16) * 32]);
        }
        __syncthreads();

        short8 af[4], bf[4];
        const int fr = lane & 15;
        const int kb = (lane >> 4) * 8;
        #pragma unroll
        for (int m = 0; m < 4; ++m)
            af[m] = *(const short8*)&As[(wr * 64 + m * 16 + fr) * 32 + kb];
        #pragma unroll
        for (int n = 0; n < 4; ++n)
            bf[n] = *(const short8*)&Bs[(wc * 64 + n * 16 + fr) * 32 + kb];

        #pragma unroll
        for (int m = 0; m < 4; ++m)
            #pragma unroll
            for (int n = 0; n < 4; ++n)
                acc[m][n] = __builtin_amdgcn_mfma_f32_16x16x32_bf16(
                    af[m], bf[n], acc[m][n], 0, 0, 0);
        __syncthreads();
    }

    float* Cb; int ldc, cb;
    if (col0 < split) { Cb = C0; ldc = split;     cb = col0; }
    else              { Cb = C1; ldc = N - split; cb = col0 - split; }

    const int crow = (lane >> 4) * 4;
    const int ccol = lane & 15;
    #pragma unroll
    for (int m = 0; m < 4; ++m) {
        #pragma unroll
        for (int n = 0; n < 4; ++n) {
            float* cp = Cb + (size_t)(row0 + wr * 64 + m * 16 + crow) * ldc
                           + cb + wc * 64 + n * 16 + ccol;
            #pragma unroll
            for (int i = 0; i < 4; ++i)
                cp[(size_t)i * ldc] = acc[m][n][i];
        }
    }
}

// ---------------------------------------------------------------------------
// fp32 -> bf16 elementwise
// ---------------------------------------------------------------------------
__global__ __launch_bounds__(256)
void f32_to_bf16(const float* __restrict__ in, ushort_t* __restrict__ out, int n) {
    int i = (blockIdx.x * 256 + threadIdx.x) * 8;
    if (i + 8 <= n) {
        float4 a = *reinterpret_cast<const float4*>(in + i);
        float4 b = *reinterpret_cast<const float4*>(in + i + 4);
        ushort_t o[8] = {f2bf(a.x), f2bf(a.y), f2bf(a.z), f2bf(a.w),
                         f2bf(b.x), f2bf(b.y), f2bf(b.z), f2bf(b.w)};
        *reinterpret_cast<short8*>(out + i) = *reinterpret_cast<short8*>(o);
    }
}

// ---------------------------------------------------------------------------
// transpose + convert: Wt[c][r] = bf16(W[r][c]).
// ---------------------------------------------------------------------------
__global__ __launch_bounds__(256)
void transp_bf16(const float* __restrict__ W, ushort_t* __restrict__ Wt,
                 int R, int C) {
    __shared__ ushort_t tile[32][33];
    int tx = threadIdx.x & 31, ty = threadIdx.x >> 5;
    int r0 = blockIdx.y * 32, c0 = blockIdx.x * 32;
    #pragma unroll
    for (int i = 0; i < 32; i += 8)
        tile[ty + i][tx] = f2bf(W[(size_t)(r0 + ty + i) * C + c0 + tx]);
    __syncthreads();
    #pragma unroll
    for (int i = 0; i < 32; i += 8)
        Wt[(size_t)(c0 + ty + i) * R + r0 + tx] = tile[tx][ty + i];
}

// ---------------------------------------------------------------------------
// Split-K GEMM for x_dbl: part[s] = u[:, s*128:(s+1)*128] @ W_xp[s*128.., :]
// ---------------------------------------------------------------------------
__global__ __launch_bounds__(256)
void gemm_xdbl_splitk(const float* __restrict__ u, const float* __restrict__ W,
                      float* __restrict__ part) {
    __shared__ float As[16][65];
    __shared__ float Bs[16][96];

    const int tid = threadIdx.x;
    const int m0 = blockIdx.x * 64;
    const int kbase = blockIdx.y * (D_INNER / KSPLIT);

    const int tx = tid & 15;
    const int ty = tid >> 4;
    const int arow = tid >> 4;
    const int acol = tid & 15;

    float acc[4][6] = {};

    for (int k0 = 0; k0 < D_INNER / KSPLIT; k0 += 16) {
        #pragma unroll
        for (int p = 0; p < 4; ++p) {
            int r = arow + p * 16;
            As[acol][r] = u[(size_t)(m0 + r) * D_INNER + kbase + k0 + acol];
        }
        #pragma unroll
        for (int j = 0; j < 6; ++j) {
            int idx = j * 256 + tid;
            int row = idx / 96, col = idx - row * 96;
            Bs[row][col] = W[(size_t)(kbase + k0 + row) * 96 + col];
        }
        __syncthreads();
        #pragma unroll
        for (int kk = 0; kk < 16; ++kk) {
            float a[4], b[6];
            #pragma unroll
            for (int i = 0; i < 4; ++i) a[i] = As[kk][ty * 4 + i];
            #pragma unroll
            for (int j = 0; j < 6; ++j) b[j] = Bs[kk][tx * 6 + j];
            #pragma unroll
            for (int i = 0; i < 4; ++i)
                #pragma unroll
                for (int j = 0; j < 6; ++j)
                    acc[i][j] = fmaf(a[i], b[j], acc[i][j]);
        }
        __syncthreads();
    }

    float* pblk = part + (size_t)blockIdx.y * BL * 96;
    #pragma unroll
    for (int i = 0; i < 4; ++i)
        #pragma unroll
        for (int j = 0; j < 6; ++j)
            pblk[(size_t)(m0 + ty * 4 + i) * 96 + tx * 6 + j] = acc[i][j];
}

__global__ __launch_bounds__(256)
void xdbl_reduce(const float* __restrict__ part, float* __restrict__ x_dbl) {
    int i = blockIdx.x * 256 + threadIdx.x;
    float s = 0.0f;
    #pragma unroll
    for (int k = 0; k < KSPLIT; ++k)
        s += part[(size_t)k * BL * 96 + i];
    x_dbl[i] = s;
}

// ---------------------------------------------------------------------------
// Generic fp32 GEMM (delta). EPI==1: C = softplus(acc + bias[col])
// ---------------------------------------------------------------------------
template<int EPI>
__global__ __launch_bounds__(256)
void gemm_f32(const float* __restrict__ A, const float* __restrict__ B,
              float* __restrict__ C, const float* __restrict__ bias,
              int M, int N, int K, int lda, int ldb, int ldc) {
    __shared__ float As[16][65];
    __shared__ float Bs[16][64];

    const int tid = threadIdx.x;
    const int tx = tid & 15;
    const int ty = tid >> 4;
    const int row0 = blockIdx.y * 64;
    const int col0 = blockIdx.x * 64;

    const int arow = tid >> 4;
    const int acol = tid & 15;
    const int brow = tid >> 6;
    const int bcol = tid & 63;

    float acc[4][4] = {};

    for (int k0 = 0; k0 < K; k0 += 16) {
        #pragma unroll
        for (int p = 0; p < 4; ++p) {
            int r = arow + p * 16;
            As[acol][r] = A[(size_t)(row0 + r) * lda + (k0 + acol)];
        }
        int gc = col0 + bcol;
        #pragma unroll
        for (int p = 0; p < 4; ++p) {
            int r = brow + p * 4;
            Bs[r][bcol] = (gc < N) ? B[(size_t)(k0 + r) * ldb + gc] : 0.0f;
        }
        __syncthreads();
        #pragma unroll
        for (int kk = 0; kk < 16; ++kk) {
            float a[4];
            #pragma unroll
            for (int i = 0; i < 4; ++i) a[i] = As[kk][ty * 4 + i];
            float4 bv = *reinterpret_cast<const float4*>(&Bs[kk][tx * 4]);
            float b4[4] = {bv.x, bv.y, bv.z, bv.w};
            #pragma unroll
            for (int i = 0; i < 4; ++i)
                #pragma unroll
                for (int j = 0; j < 4; ++j)
                    acc[i][j] = fmaf(a[i], b4[j], acc[i][j]);
        }
        __syncthreads();
    }

    #pragma unroll
    for (int i = 0; i < 4; ++i) {
        int gr = row0 + ty * 4 + i;
        #pragma unroll
        for (int j = 0; j < 4; ++j) {
            int gc = col0 + tx * 4 + j;
            if (gc < N) {
                float v = acc[i][j];
                if (EPI == 1) {
                    v += bias[gc];
                    v = (v > 20.0f) ? v : log1pf(__expf(v));
                }
                C[(size_t)gr * ldc + gc] = v;
            }
        }
    }
}

// ---------------------------------------------------------------------------
// Causal depthwise conv (K=4) + bias + SiLU. Reads xp [BL, D_INNER].
// ---------------------------------------------------------------------------
__global__ __launch_bounds__(256)
void conv_silu(const float* __restrict__ xp, const float* __restrict__ conv_w,
               const float* __restrict__ conv_b, float* __restrict__ u) {
    int idx = blockIdx.x * 256 + threadIdx.x;
    if (idx >= BL * D_INNER) return;
    int e  = idx & (D_INNER - 1);
    int bl = idx >> 11;
    int b = bl >> 10, l = bl & (LL - 1);
    float acc = conv_b[e];
    #pragma unroll
    for (int k = 0; k < D_CONV; ++k) {
        int ll = l - (D_CONV - 1) + k;
        if (ll >= 0)
            acc = fmaf(conv_w[e * D_CONV + k],
                       xp[(size_t)(b * LL + ll) * D_INNER + e], acc);
    }
    u[idx] = acc * sigmoidf_(acc);
}

// ---------------------------------------------------------------------------
// Chunked selective scan, thread-per-(b,e,chunk), 16 states in registers.
// g = [b:1][c:6][e:11] (e fastest -> coalesced delta/u/z; B/C broadcast).
// hend layout: [c][b][n][e] (store/load coalesced over e).
// sumdelta layout: [c][b][e].
// ---------------------------------------------------------------------------
__global__ __launch_bounds__(256)
void scan_phase1(const float* __restrict__ delta, const float* __restrict__ u_in,
                 const float* __restrict__ x_dbl, const float* __restrict__ A_log,
                 float* __restrict__ hend, float* __restrict__ sumdelta) {
    int g = blockIdx.x * 256 + threadIdx.x;
    int e = g & (D_INNER - 1);
    int c = (g >> 11) & (NCHUNK - 1);
    int b = g >> 17;

    float A_en[D_STATE];
    #pragma unroll
    for (int n = 0; n < D_STATE; n += 4) {
        float4 al = *(const float4*)&A_log[e * D_STATE + n];
        A_en[n]     = -__expf(al.x);
        A_en[n + 1] = -__expf(al.y);
        A_en[n + 2] = -__expf(al.z);
        A_en[n + 3] = -__expf(al.w);
    }

    float h[D_STATE];
    #pragma unroll
    for (int n = 0; n < D_STATE; ++n) h[n] = 0.0f;
    float S = 0.0f;

    const int t0 = c * CHUNK;
    const float* dptr = delta + (size_t)(b * LL + t0) * D_INNER + e;
    const float* uptr = u_in  + (size_t)(b * LL + t0) * D_INNER + e;
    const float* xb   = x_dbl + (size_t)(b * LL + t0) * 96 + DT_RANK;

    for (int t = 0; t < CHUNK; ++t) {
        float dv = dptr[(size_t)t * D_INNER];
        float uv = uptr[(size_t)t * D_INNER];
        const float* xrow = xb + (size_t)t * 96;
        float4 B0 = *(const float4*)(xrow);
        float4 B1 = *(const float4*)(xrow + 4);
        float4 B2 = *(const float4*)(xrow + 8);
        float4 B3 = *(const float4*)(xrow + 12);
        float Bv[16] = {B0.x, B0.y, B0.z, B0.w, B1.x, B1.y, B1.z, B1.w,
                        B2.x, B2.y, B2.z, B2.w, B3.x, B3.y, B3.z, B3.w};
        S += dv;
        float du = dv * uv;
        #pragma unroll
        for (int n = 0; n < D_STATE; ++n) {
            float dA = __expf(dv * A_en[n]);
            h[n] = fmaf(dA, h[n], du * Bv[n]);
        }
    }

    size_t rbase = ((size_t)(c * BB + b) * D_STATE) * D_INNER + e;
    #pragma unroll
    for (int n = 0; n < D_STATE; ++n)
        hend[rbase + (size_t)n * D_INNER] = h[n];
    sumdelta[(size_t)(c * BB + b) * D_INNER + e] = S;
}

// In-place: hh holds hend on entry, hin on exit. Thread owns (b,n,e) slots.
__global__ __launch_bounds__(256)
void scan_phase2(const float* __restrict__ A_log, const float* __restrict__ sumdelta,
                 float* __restrict__ hh) {
    int g = blockIdx.x * 256 + threadIdx.x;   // (b*16+n)*2048 + e
    int e = g & (D_INNER - 1);
    int n = (g >> 11) & (D_STATE - 1);
    int b = g >> 15;
    float A_en = -__expf(A_log[e * D_STATE + n]);
    float h = 0.0f;
    for (int c = 0; c < NCHUNK; ++c) {
        size_t idx = ((size_t)(c * BB + b) * D_STATE + n) * D_INNER + e;
        float he = hh[idx];
        float dA = __expf(A_en * sumdelta[(size_t)(c * BB + b) * D_INNER + e]);
        hh[idx] = h;
        h = fmaf(dA, h, he);
    }
}

__global__ __launch_bounds__(256)
void scan_phase3(const float* __restrict__ delta, const float* __restrict__ u_in,
                 const float* __restrict__ x_dbl, const float* __restrict__ z,
                 const float* __restrict__ A_log, const float* __restrict__ D_skip,
                 const float* __restrict__ hin, ushort_t* __restrict__ ybf) {
    int g = blockIdx.x * 256 + threadIdx.x;
    int e = g & (D_INNER - 1);
    int c = (g >> 11) & (NCHUNK - 1);
    int b = g >> 17;

    float A_en[D_STATE];
    #pragma unroll
    for (int n = 0; n < D_STATE; n += 4) {
        float4 al = *(const float4*)&A_log[e * D_STATE + n];
        A_en[n]     = -__expf(al.x);
        A_en[n + 1] = -__expf(al.y);
        A_en[n + 2] = -__expf(al.z);
        A_en[n + 3] = -__expf(al.w);
    }
    float D_e = D_skip[e];

    float h[D_STATE];
    size_t rbase = ((size_t)(c * BB + b) * D_STATE) * D_INNER + e;
    #pragma unroll
    for (int n = 0; n < D_STATE; ++n)
        h[n] = hin[rbase + (size_t)n * D_INNER];

    const int t0 = c * CHUNK;
    const float* dptr = delta + (size_t)(b * LL + t0) * D_INNER + e;
    const float* uptr = u_in  + (size_t)(b * LL + t0) * D_INNER + e;
    const float* xb   = x_dbl + (size_t)(b * LL + t0) * 96 + DT_RANK;
    const float* zptr = z     + (size_t)(b * LL + t0) * D_INNER + e;
    ushort_t* yout = ybf + (size_t)(b * LL + t0) * D_INNER + e;

    for (int t = 0; t < CHUNK; ++t) {
        float dv = dptr[(size_t)t * D_INNER];
        float uv = uptr[(size_t)t * D_INNER];
        const float* xrow = xb + (size_t)t * 96;
        float4 B0 = *(const float4*)(xrow);
        float4 B1 = *(const float4*)(xrow + 4);
        float4 B2 = *(const float4*)(xrow + 8);
        float4 B3 = *(const float4*)(xrow + 12);
        float4 C0 = *(const float4*)(xrow + 16);
        float4 C1 = *(const float4*)(xrow + 20);
        float4 C2 = *(const float4*)(xrow + 24);
        float4 C3 = *(const float4*)(xrow + 28);
        float Bv[16] = {B0.x, B0.y, B0.z, B0.w, B1.x, B1.y, B1.z, B1.w,
                        B2.x, B2.y, B2.z, B2.w, B3.x, B3.y, B3.z, B3.w};
        float Cv[16] = {C0.x, C0.y, C0.z, C0.w, C1.x, C1.y, C1.z, C1.w,
                        C2.x, C2.y, C2.z, C2.w, C3.x, C3.y, C3.z, C3.w};
        float du = dv * uv;
        float y = 0.0f;
        #pragma unroll
        for (int n = 0; n < D_STATE; ++n) {
            float dA = __expf(dv * A_en[n]);
            h[n] = fmaf(dA, h[n], du * Bv[n]);
            y = fmaf(h[n], Cv[n], y);
        }
        float zv = zptr[(size_t)t * D_INNER];
        float yg = (y + uv * D_e) * (zv * sigmoidf_(zv));
        yout[(size_t)t * D_INNER] = f2bf(yg);
    }
}

// ---------------------------------------------------------------------------
extern "C" void kernel_launch(void* const* d_in, const int* in_sizes, int n_in,
                              void* d_out, int out_size, void* d_ws, size_t ws_size,
                              hipStream_t stream) {
    const float* x      = (const float*)d_in[0];
    const float* W_in   = (const float*)d_in[1];
    const float* conv_w = (const float*)d_in[2];
    const float* conv_b = (const float*)d_in[3];
    const float* W_xp   = (const float*)d_in[4];
    const float* W_dt   = (const float*)d_in[5];
    const float* dt_b   = (const float*)d_in[6];
    const float* A_log  = (const float*)d_in[7];
    const float* D_skip = (const float*)d_in[8];
    const float* W_out  = (const float*)d_in[9];
    float* out = (float*)d_out;

    // workspace layout (floats), peak 18.44M floats = 73.8 MB:
    const size_t M1 = 1024 * 1024;
    float* ws    = (float*)d_ws;
    float* z     = ws;                    // 4M  [step1 -> phase3]
    float* hend  = ws + 4 * M1;           // 4M  [phase1 -> phase3]; xp alias pre-scan
    float* xp    = hend;                  //     [step1 -> step2] (dead before phase1)
    float* u     = ws + 8 * M1;           // 4M  [step2 -> phase3]
    float* x_dbl = ws + 12 * M1;          // 192K [step3 -> phase3]
    float* delta = x_dbl + (size_t)BL * 96;        // 4M [step4 -> phase3]
    float* sumd  = delta + 4 * M1;        // 256K [phase1 -> phase2]
    ushort_t* ybf = (ushort_t*)(sumd + BB * NCHUNK * D_INNER); // 2M-float [p3 -> 6]

    // time-disjoint aliases inside the delta region (dead until step 4):
    ushort_t* Wint_bf   = (ushort_t*)delta;            // [0b -> 1]
    ushort_t* x_bf      = (ushort_t*)(delta + 2 * M1); // [0a -> 1]
    float*    xdbl_part = delta;                       // [step 3]
    // Woutt_bf aliases hend/hin (dead after phase3):
    ushort_t* Woutt_bf  = (ushort_t*)hend;             // [5b -> 6]

    dim3 blk(256);

    // 0a) x -> bf16
    hipLaunchKernelGGL(f32_to_bf16, dim3((BL * D_MODEL) / (256 * 8)), blk, 0, stream,
                       x, x_bf, BL * D_MODEL);
    // 0b) W_in [1024,4096] -> Wint_bf [4096,1024]
    hipLaunchKernelGGL(transp_bf16, dim3(4096 / 32, 1024 / 32), blk, 0, stream,
                       W_in, Wint_bf, 1024, 4096);
    // 1) [xp | z] = x @ W_in   (bf16 MFMA, column-split epilogue)
    hipLaunchKernelGGL(gemm_bf16, dim3(4096 / 128, BL / 128), blk, 0, stream,
                       x_bf, Wint_bf, xp, z, BL, 2 * D_INNER, D_MODEL, D_INNER);
    // 2) u = silu(convdw(xp) + b)
    hipLaunchKernelGGL(conv_silu, dim3((BL * D_INNER) / 256), blk, 0, stream,
                       xp, conv_w, conv_b, u);
    // 3) x_dbl = u @ W_xp   (fp32 split-K)
    hipLaunchKernelGGL(gemm_xdbl_splitk, dim3(BL / 64, KSPLIT), blk, 0, stream,
                       u, W_xp, xdbl_part);
    hipLaunchKernelGGL(xdbl_reduce, dim3((BL * 96) / 256), blk, 0, stream,
                       xdbl_part, x_dbl);
    // 4) delta = softplus(x_dbl[:, :64] @ W_dt + dt_bias)
    hipLaunchKernelGGL((gemm_f32<1>), dim3(D_INNER / 64, BL / 64), blk, 0, stream,
                       x_dbl, W_dt, delta, dt_b, BL, D_INNER, DT_RANK, 96, D_INNER, D_INNER);
    // 5) chunked selective scan + gate -> ybf (bf16)
    hipLaunchKernelGGL(scan_phase1, dim3((BB * NCHUNK * D_INNER) / 256), blk, 0, stream,
                       delta, u, x_dbl, A_log, hend, sumd);
    hipLaunchKernelGGL(scan_phase2, dim3((BB * D_STATE * D_INNER) / 256), blk, 0, stream,
                       A_log, sumd, hend);
    hipLaunchKernelGGL(scan_phase3, dim3((BB * NCHUNK * D_INNER) / 256), blk, 0, stream,
                       delta, u, x_dbl, z, A_log, D_skip, hend, ybf);
    // 5b) W_out [2048,1024] -> Woutt_bf [1024,2048]  (hin dead)
    hipLaunchKernelGGL(transp_bf16, dim3(1024 / 32, 2048 / 32), blk, 0, stream,
                       W_out, Woutt_bf, 2048, 1024);
    // 6) out = ybf @ W_out   (bf16 MFMA, single output)
    hipLaunchKernelGGL(gemm_bf16, dim3(D_MODEL / 128, BL / 128), blk, 0, stream,
                       ybf, Woutt_bf, out, out, BL, D_MODEL, D_INNER, D_MODEL);
}